// Round 1
// baseline (502.736 us; speedup 1.0000x reference)
//
#include <hip/hip_runtime.h>

// BlockResMLP MixerBlock: 2 layers of 64 independent block MLPs (64->128->64, ELU, residual)
// with a per-row 64x64 transpose (shuffle) around layer 2.
// Strategy: bf16 MFMA (16x16x32), fp32 accumulate. 4 kernels:
//   k0: weight convert+transpose to bf16 fragment-friendly layouts
//   k1: layer-1 facto, writes y1 in transposed layout [j][n][r] (bf16)
//   k2: layer-2 facto on transposed data, writes y2 [m][r][i] (bf16)
//   k3: inverse shuffle + bf16->fp32 output

typedef short short8 __attribute__((ext_vector_type(8)));
typedef float floatx4 __attribute__((ext_vector_type(4)));

#define MFMA(A, B, C) __builtin_amdgcn_mfma_f32_16x16x32_bf16((A), (B), (C), 0, 0, 0)

__device__ __forceinline__ unsigned short bf16r(float f) {
  unsigned int u = __builtin_bit_cast(unsigned int, f);
  u += 0x7FFFu + ((u >> 16) & 1u);   // round-to-nearest-even
  return (unsigned short)(u >> 16);
}
__device__ __forceinline__ float bf16f(unsigned short h) {
  unsigned int u = ((unsigned int)h) << 16;
  return __builtin_bit_cast(float, u);
}
__device__ __forceinline__ float eluf(float v) {
  return v > 0.f ? v : (__expf(v) - 1.f);
}

// ---------------- K0: weight prep ----------------
// w1 fp32 [l][n][d][e] (2,64,64,128)  -> w1t bf16 [l*64+n][e][d]
// w2 fp32 [l][n][e][d'] (2,64,128,64) -> w2t bf16 [l*64+n][d'][e]
__global__ __launch_bounds__(256) void k0_prep(const float* __restrict__ w1,
                                               const float* __restrict__ w2,
                                               short* __restrict__ w1t,
                                               short* __restrict__ w2t) {
  int tid = blockIdx.x * 256 + threadIdx.x;     // grid 4096 -> tid < 2^20
  int d  = tid & 63;
  int e  = (tid >> 6) & 127;
  int ln = tid >> 13;                           // 0..127
  w1t[tid] = (short)bf16r(w1[((size_t)ln * 64 + d) * 128 + e]);
  int e2 = tid & 127;
  int dp = (tid >> 7) & 63;
  w2t[tid] = (short)bf16r(w2[((size_t)ln * 128 + e2) * 64 + dp]);
}

// ---------------- K1: layer 0 facto ----------------
// WG = (n-pair x 64 rows), 4 waves, wave = (n-of-pair, row-half of 32 = 2 Mtiles).
// Writes y1[j][n][r] bf16 (j = layer1 elem, n = layer1 block, r = row), r contiguous.
__global__ __launch_bounds__(256) void k1_layer0(
    const float* __restrict__ x,
    const short* __restrict__ w1t, const short* __restrict__ w2t,
    const float* __restrict__ b1,  const float* __restrict__ b2,
    short* __restrict__ y1) {
  __shared__ __align__(16) short hst[4][2][16][72];   // per-wave, per-Mtile h stage
  const int tid  = threadIdx.x;
  const int lane = tid & 63;
  const int wv   = tid >> 6;
  const int il   = lane & 15;
  const int q    = lane >> 4;
  const int npair   = blockIdx.x & 31;
  const int rowtile = blockIdx.x >> 5;
  const int n  = npair * 2 + (wv & 1);
  const int r0 = rowtile * 64 + (wv >> 1) * 32;

  const short* w1n = w1t + (size_t)n * 8192;    // [e][d] for layer 0
  const short* w2n = w2t + (size_t)n * 8192;    // [d'][e]
  const float* b1n = b1 + n * 128;
  const float* b2n = b2 + n * 64;

  floatx4 acc2[2][4] = {};
  for (int hh = 0; hh < 2; ++hh) {              // N-half of GEMM1 / K-half of GEMM2
    floatx4 acc1[2][4] = {};
#pragma unroll
    for (int ks = 0; ks < 2; ++ks) {
      short8 a[2];
#pragma unroll
      for (int Mt = 0; Mt < 2; ++Mt) {
        const float* xp = x + (size_t)(r0 + Mt * 16 + il) * 4096 + n * 64 + ks * 32 + q * 8;
        floatx4 f0 = *(const floatx4*)xp;
        floatx4 f1 = *(const floatx4*)(xp + 4);
        short8 t;
#pragma unroll
        for (int u = 0; u < 4; ++u) { t[u] = (short)bf16r(f0[u]); t[4 + u] = (short)bf16r(f1[u]); }
        a[Mt] = t;
      }
#pragma unroll
      for (int nt = 0; nt < 4; ++nt) {
        short8 b = *(const short8*)(w1n + (hh * 64 + nt * 16 + il) * 64 + ks * 32 + q * 8);
        acc1[0][nt] = MFMA(a[0], b, acc1[0][nt]);
        acc1[1][nt] = MFMA(a[1], b, acc1[1][nt]);
      }
    }
    // epilogue 1: bias + ELU -> h stage (bf16)
#pragma unroll
    for (int nt = 0; nt < 4; ++nt) {
      float bias = b1n[hh * 64 + nt * 16 + il];
#pragma unroll
      for (int Mt = 0; Mt < 2; ++Mt)
#pragma unroll
        for (int rg = 0; rg < 4; ++rg) {
          float v = acc1[Mt][nt][rg] + bias;
          hst[wv][Mt][q * 4 + rg][nt * 16 + il] = (short)bf16r(eluf(v));
        }
    }
    asm volatile("s_waitcnt lgkmcnt(0)" ::: "memory");
    // GEMM2 partial (this hh's 64 K-columns)
#pragma unroll
    for (int ks2 = 0; ks2 < 2; ++ks2) {
      short8 a2[2];
      a2[0] = *(const short8*)&hst[wv][0][il][ks2 * 32 + q * 8];
      a2[1] = *(const short8*)&hst[wv][1][il][ks2 * 32 + q * 8];
#pragma unroll
      for (int nt2 = 0; nt2 < 4; ++nt2) {
        short8 b = *(const short8*)(w2n + (nt2 * 16 + il) * 128 + hh * 64 + ks2 * 32 + q * 8);
        acc2[0][nt2] = MFMA(a2[0], b, acc2[0][nt2]);
        acc2[1][nt2] = MFMA(a2[1], b, acc2[1][nt2]);
      }
    }
    asm volatile("s_waitcnt lgkmcnt(0)" ::: "memory");   // reads done before next hh overwrite
  }
  // epilogue 2: bias + fp32 residual from x, reg-pack 4 consecutive rows -> b64 store
#pragma unroll
  for (int Mt = 0; Mt < 2; ++Mt) {
    const int R0 = r0 + Mt * 16 + q * 4;
#pragma unroll
    for (int nt2 = 0; nt2 < 4; ++nt2) {
      const int j = nt2 * 16 + il;
      const float bias = b2n[j];
      float v0 = acc2[Mt][nt2][0] + bias + x[(size_t)(R0 + 0) * 4096 + n * 64 + j];
      float v1 = acc2[Mt][nt2][1] + bias + x[(size_t)(R0 + 1) * 4096 + n * 64 + j];
      float v2 = acc2[Mt][nt2][2] + bias + x[(size_t)(R0 + 2) * 4096 + n * 64 + j];
      float v3 = acc2[Mt][nt2][3] + bias + x[(size_t)(R0 + 3) * 4096 + n * 64 + j];
      uint2 pk;
      pk.x = (unsigned int)bf16r(v0) | ((unsigned int)bf16r(v1) << 16);
      pk.y = (unsigned int)bf16r(v2) | ((unsigned int)bf16r(v3) << 16);
      *(uint2*)(y1 + ((size_t)(j * 64 + n) * 8192 + R0)) = pk;
    }
  }
}

// ---------------- K2: layer 1 facto (on transposed data) ----------------
// z2(block m, elem i, row r) = y1[(m*64+i)*8192 + r]. WG = (m-pair x 32 rows), 4 waves.
// Writes y2[m][r][i] bf16.
__global__ __launch_bounds__(256) void k2_layer1(
    const short* __restrict__ y1,
    const short* __restrict__ w1t, const short* __restrict__ w2t,
    const float* __restrict__ b1,  const float* __restrict__ b2,
    short* __restrict__ y2) {
  __shared__ __align__(16) short hst[4][16][72];
  const int tid  = threadIdx.x;
  const int lane = tid & 63;
  const int wv   = tid >> 6;
  const int il   = lane & 15;
  const int q    = lane >> 4;
  const int mpair   = blockIdx.x & 31;
  const int rowtile = blockIdx.x >> 5;
  const int m  = mpair * 2 + (wv & 1);
  const int r0 = rowtile * 32 + (wv >> 1) * 16;

  const short* w1m = w1t + (size_t)(64 + m) * 8192;   // layer 1 weights
  const short* w2m = w2t + (size_t)(64 + m) * 8192;
  const float* b1m = b1 + (64 + m) * 128;
  const float* b2m = b2 + (64 + m) * 64;

  floatx4 acc2[4] = {};
  for (int hh = 0; hh < 2; ++hh) {
    floatx4 acc1[4] = {};
#pragma unroll
    for (int ks = 0; ks < 2; ++ks) {
      const short* zp = y1 + ((size_t)(m * 64 + ks * 32 + q * 8)) * 8192 + (r0 + il);
      short8 a;
#pragma unroll
      for (int jj = 0; jj < 8; ++jj) a[jj] = zp[(size_t)jj * 8192];
#pragma unroll
      for (int nt = 0; nt < 4; ++nt) {
        short8 b = *(const short8*)(w1m + (hh * 64 + nt * 16 + il) * 64 + ks * 32 + q * 8);
        acc1[nt] = MFMA(a, b, acc1[nt]);
      }
    }
#pragma unroll
    for (int nt = 0; nt < 4; ++nt) {
      float bias = b1m[hh * 64 + nt * 16 + il];
#pragma unroll
      for (int rg = 0; rg < 4; ++rg) {
        float v = acc1[nt][rg] + bias;
        hst[wv][q * 4 + rg][nt * 16 + il] = (short)bf16r(eluf(v));
      }
    }
    asm volatile("s_waitcnt lgkmcnt(0)" ::: "memory");
#pragma unroll
    for (int ks2 = 0; ks2 < 2; ++ks2) {
      short8 a2 = *(const short8*)&hst[wv][il][ks2 * 32 + q * 8];
#pragma unroll
      for (int nt2 = 0; nt2 < 4; ++nt2) {
        short8 b = *(const short8*)(w2m + (nt2 * 16 + il) * 128 + hh * 64 + ks2 * 32 + q * 8);
        acc2[nt2] = MFMA(a2, b, acc2[nt2]);
      }
    }
    asm volatile("s_waitcnt lgkmcnt(0)" ::: "memory");
  }
  // epilogue: bias + residual (bf16 z2 from y1, 4 consecutive rows = b64), restage [row][i]
#pragma unroll
  for (int nt2 = 0; nt2 < 4; ++nt2) {
    const int j = nt2 * 16 + il;
    const float bias = b2m[j];
    const uint2 zr = *(const uint2*)(y1 + (size_t)(m * 64 + j) * 8192 + (r0 + q * 4));
    hst[wv][q * 4 + 0][j] = (short)bf16r(acc2[nt2][0] + bias + bf16f((unsigned short)(zr.x & 0xFFFF)));
    hst[wv][q * 4 + 1][j] = (short)bf16r(acc2[nt2][1] + bias + bf16f((unsigned short)(zr.x >> 16)));
    hst[wv][q * 4 + 2][j] = (short)bf16r(acc2[nt2][2] + bias + bf16f((unsigned short)(zr.y & 0xFFFF)));
    hst[wv][q * 4 + 3][j] = (short)bf16r(acc2[nt2][3] + bias + bf16f((unsigned short)(zr.y >> 16)));
  }
  asm volatile("s_waitcnt lgkmcnt(0)" ::: "memory");
  // coop store to y2[m][r][i], b64 per lane
  const int rr = lane & 15;
  const int iq = lane >> 4;
#pragma unroll
  for (int t = 0; t < 4; ++t) {
    const uint2 v = *(const uint2*)&hst[wv][rr][t * 16 + iq * 4];
    *(uint2*)(y2 + ((size_t)(m * 8192 + r0 + rr)) * 64 + t * 16 + iq * 4) = v;
  }
}

// ---------------- K3: inverse shuffle + fp32 output ----------------
// out[r][i*64 + m] = y2[m][r][i].  WG = 4 rows, wave per row, LDS 64x64 transpose.
__global__ __launch_bounds__(256) void k3_unshuffle(
    const short* __restrict__ y2, float* __restrict__ out) {
  __shared__ __align__(16) short st[4][64][68];
  const int tid  = threadIdx.x;
  const int lane = tid & 63;
  const int wv   = tid >> 6;
  const int R    = blockIdx.x * 4 + wv;
  const int mq = lane >> 2;   // 0..15
  const int iq = lane & 3;    // 0..3
#pragma unroll
  for (int mt = 0; mt < 4; ++mt) {
#pragma unroll
    for (int it = 0; it < 4; ++it) {
      const int mm = mt * 16 + mq;
      const int i  = it * 16 + iq * 4;
      const uint2 v = *(const uint2*)(y2 + ((size_t)(mm * 8192 + R)) * 64 + i);
      *(uint2*)&st[wv][mm][i] = v;
    }
  }
  asm volatile("s_waitcnt vmcnt(0) lgkmcnt(0)" ::: "memory");
  float* orow = out + (size_t)R * 4096;
#pragma unroll 4
  for (int i = 0; i < 64; ++i) {
    orow[i * 64 + lane] = bf16f((unsigned short)st[wv][lane][i]);
  }
}

extern "C" void kernel_launch(void* const* d_in, const int* in_sizes, int n_in,
                              void* d_out, int out_size, void* d_ws, size_t ws_size,
                              hipStream_t stream) {
  const float* x  = (const float*)d_in[0];
  const float* w1 = (const float*)d_in[1];
  const float* b1 = (const float*)d_in[2];
  const float* w2 = (const float*)d_in[3];
  const float* b2 = (const float*)d_in[4];
  float* out = (float*)d_out;

  // workspace carve-up (shorts): w1t 1M, w2t 1M, y1 32M, y2 32M  -> ~138 MB total
  short* w1t = (short*)d_ws;
  short* w2t = w1t + (1u << 20);
  short* y1  = w2t + (1u << 20);
  short* y2  = y1 + (1ull << 25);

  hipLaunchKernelGGL(k0_prep,      dim3(4096), dim3(256), 0, stream, w1, w2, w1t, w2t);
  hipLaunchKernelGGL(k1_layer0,    dim3(4096), dim3(256), 0, stream, x, w1t, w2t, b1, b2, y1);
  hipLaunchKernelGGL(k2_layer1,    dim3(8192), dim3(256), 0, stream, y1, w1t, w2t, b1, b2, y2);
  hipLaunchKernelGGL(k3_unshuffle, dim3(2048), dim3(256), 0, stream, y2, out);
}

// Round 2
// 466.256 us; speedup vs baseline: 1.0782x; 1.0782x over previous
//
#include <hip/hip_runtime.h>

// BlockResMLP MixerBlock: 2 layers of 64 independent block MLPs (64->128->64, ELU, residual)
// with a per-row 64x64 transpose (shuffle) around layer 2.
// Strategy: bf16 MFMA (16x16x32), fp32 accumulate. 4 kernels:
//   k0: weight convert+transpose to bf16 fragment-friendly layouts
//   k1: layer-1 facto, writes y1 in layout [row>>5][n][j][row&31] (coalesced uint2 stores)
//   k2: layer-2 facto: chunked y1 loads -> LDS transpose -> b128 frags; writes y2 [m][row][i]
//   k3: inverse shuffle + bf16->fp32 output

typedef short short8 __attribute__((ext_vector_type(8)));
typedef float floatx4 __attribute__((ext_vector_type(4)));

#define MFMA(A, B, C) __builtin_amdgcn_mfma_f32_16x16x32_bf16((A), (B), (C), 0, 0, 0)

__device__ __forceinline__ unsigned short bf16r(float f) {
  unsigned int u = __builtin_bit_cast(unsigned int, f);
  u += 0x7FFFu + ((u >> 16) & 1u);   // round-to-nearest-even
  return (unsigned short)(u >> 16);
}
__device__ __forceinline__ float bf16f(unsigned short h) {
  unsigned int u = ((unsigned int)h) << 16;
  return __builtin_bit_cast(float, u);
}
__device__ __forceinline__ float eluf(float v) {
  return v > 0.f ? v : (__expf(v) - 1.f);
}

// ---------------- K0: weight prep ----------------
// w1 fp32 [l][n][d][e] (2,64,64,128)  -> w1t bf16 [l*64+n][e][d]
// w2 fp32 [l][n][e][d'] (2,64,128,64) -> w2t bf16 [l*64+n][d'][e]
__global__ __launch_bounds__(256) void k0_prep(const float* __restrict__ w1,
                                               const float* __restrict__ w2,
                                               short* __restrict__ w1t,
                                               short* __restrict__ w2t) {
  int tid = blockIdx.x * 256 + threadIdx.x;
  int d  = tid & 63;
  int e  = (tid >> 6) & 127;
  int ln = tid >> 13;
  w1t[tid] = (short)bf16r(w1[((size_t)ln * 64 + d) * 128 + e]);
  int e2 = tid & 127;
  int dp = (tid >> 7) & 63;
  w2t[tid] = (short)bf16r(w2[((size_t)ln * 128 + e2) * 64 + dp]);
}

// ---------------- K1: layer 0 facto ----------------
// WG = (n-pair x 64 rows), 4 waves. A-frags hoisted (load+convert x once).
// y1 layout: [row>>5][n][j][row&31] bf16  -> stores are lane-coalesced uint2.
__global__ __launch_bounds__(256) void k1_layer0(
    const float* __restrict__ x,
    const short* __restrict__ w1t, const short* __restrict__ w2t,
    const float* __restrict__ b1,  const float* __restrict__ b2,
    short* __restrict__ y1) {
  __shared__ __align__(16) short hst[4][2][16][72];
  const int tid  = threadIdx.x;
  const int lane = tid & 63;
  const int wv   = tid >> 6;
  const int il   = lane & 15;
  const int q    = lane >> 4;
  const int npair   = blockIdx.x & 31;
  const int rowtile = blockIdx.x >> 5;
  const int n  = npair * 2 + (wv & 1);
  const int r0 = rowtile * 64 + (wv >> 1) * 32;     // 32-row aligned

  const short* w1n = w1t + (size_t)n * 8192;
  const short* w2n = w2t + (size_t)n * 8192;
  const float* b1n = b1 + n * 128;
  const float* b2n = b2 + n * 64;

  // hoisted A-frags: load + convert x once (was 2x inside hh loop)
  short8 a[2][2];   // [ks][Mt]
#pragma unroll
  for (int Mt = 0; Mt < 2; ++Mt) {
#pragma unroll
    for (int ks = 0; ks < 2; ++ks) {
      const float* xp = x + (size_t)(r0 + Mt * 16 + il) * 4096 + n * 64 + ks * 32 + q * 8;
      floatx4 f0 = *(const floatx4*)xp;
      floatx4 f1 = *(const floatx4*)(xp + 4);
      short8 t;
#pragma unroll
      for (int u = 0; u < 4; ++u) { t[u] = (short)bf16r(f0[u]); t[4 + u] = (short)bf16r(f1[u]); }
      a[ks][Mt] = t;
    }
  }

  floatx4 acc2[2][4] = {};
  for (int hh = 0; hh < 2; ++hh) {
    floatx4 acc1[2][4] = {};
#pragma unroll
    for (int ks = 0; ks < 2; ++ks) {
#pragma unroll
      for (int nt = 0; nt < 4; ++nt) {
        short8 b = *(const short8*)(w1n + (hh * 64 + nt * 16 + il) * 64 + ks * 32 + q * 8);
        acc1[0][nt] = MFMA(a[ks][0], b, acc1[0][nt]);
        acc1[1][nt] = MFMA(a[ks][1], b, acc1[1][nt]);
      }
    }
    // epilogue 1: bias + ELU -> h stage (bf16)
#pragma unroll
    for (int nt = 0; nt < 4; ++nt) {
      float bias = b1n[hh * 64 + nt * 16 + il];
#pragma unroll
      for (int Mt = 0; Mt < 2; ++Mt)
#pragma unroll
        for (int rg = 0; rg < 4; ++rg) {
          float v = acc1[Mt][nt][rg] + bias;
          hst[wv][Mt][q * 4 + rg][nt * 16 + il] = (short)bf16r(eluf(v));
        }
    }
    asm volatile("s_waitcnt lgkmcnt(0)" ::: "memory");
#pragma unroll
    for (int ks2 = 0; ks2 < 2; ++ks2) {
      short8 a2[2];
      a2[0] = *(const short8*)&hst[wv][0][il][ks2 * 32 + q * 8];
      a2[1] = *(const short8*)&hst[wv][1][il][ks2 * 32 + q * 8];
#pragma unroll
      for (int nt2 = 0; nt2 < 4; ++nt2) {
        short8 b = *(const short8*)(w2n + (nt2 * 16 + il) * 128 + hh * 64 + ks2 * 32 + q * 8);
        acc2[0][nt2] = MFMA(a2[0], b, acc2[0][nt2]);
        acc2[1][nt2] = MFMA(a2[1], b, acc2[1][nt2]);
      }
    }
    asm volatile("s_waitcnt lgkmcnt(0)" ::: "memory");
  }
  // epilogue 2: bias + fp32 residual from x (L1/L2-hot: same tile as A loads),
  // store to y1[(r0>>5)][n][j][row32] -- coalesced uint2
  const size_t nbase = ((size_t)(r0 >> 5) * 64 + n) * 64;
#pragma unroll
  for (int Mt = 0; Mt < 2; ++Mt) {
    const int R0 = r0 + Mt * 16 + q * 4;
#pragma unroll
    for (int nt2 = 0; nt2 < 4; ++nt2) {
      const int j = nt2 * 16 + il;
      const float bias = b2n[j];
      float v0 = acc2[Mt][nt2][0] + bias + x[(size_t)(R0 + 0) * 4096 + n * 64 + j];
      float v1 = acc2[Mt][nt2][1] + bias + x[(size_t)(R0 + 1) * 4096 + n * 64 + j];
      float v2 = acc2[Mt][nt2][2] + bias + x[(size_t)(R0 + 2) * 4096 + n * 64 + j];
      float v3 = acc2[Mt][nt2][3] + bias + x[(size_t)(R0 + 3) * 4096 + n * 64 + j];
      uint2 pk;
      pk.x = (unsigned int)bf16r(v0) | ((unsigned int)bf16r(v1) << 16);
      pk.y = (unsigned int)bf16r(v2) | ((unsigned int)bf16r(v3) << 16);
      *(uint2*)(y1 + (nbase + j) * 32 + Mt * 16 + q * 4) = pk;
    }
  }
}

// ---------------- K2: layer 1 facto ----------------
// WG = (m, 64 rows), 4 waves (one 16-row Mtile each).
// Load: each thread reads one full 64B y1 chunk (2x uint4) -> LDS transpose zL[row][i].
// Frags: conflict-free ds_read_b128 from zL. Residual from zL. y2 [m][row][i] staged store.
__global__ __launch_bounds__(256) void k2_layer1(
    const short* __restrict__ y1,
    const short* __restrict__ w1t, const short* __restrict__ w2t,
    const float* __restrict__ b1,  const float* __restrict__ b2,
    short* __restrict__ y2) {
  __shared__ __align__(16) short zL[64][72];
  __shared__ __align__(16) short hs[4][16][72];
  const int tid  = threadIdx.x;
  const int lane = tid & 63;
  const int wv   = tid >> 6;
  const int il   = lane & 15;
  const int q    = lane >> 4;
  const int m  = blockIdx.x & 63;
  const int R0 = (blockIdx.x >> 6) * 64;

  // ---- load z2 tile: z2[row][i] = y1[row>>5][i][m][row&31] ----
  {
    const int i    = tid & 63;
    const int half = tid >> 6;           // rows half*16 .. half*16+15
    const short* src = y1 + (((size_t)((R0 >> 5) + (half >> 1)) * 64 + i) * 64 + m) * 32 + (half & 1) * 16;
    uint4 v0 = *(const uint4*)src;
    uint4 v1 = *(const uint4*)(src + 8);
    const short* p0 = (const short*)&v0;
    const short* p1 = (const short*)&v1;
#pragma unroll
    for (int k = 0; k < 8; ++k) zL[half * 16 + k][i] = p0[k];
#pragma unroll
    for (int k = 0; k < 8; ++k) zL[half * 16 + 8 + k][i] = p1[k];
  }
  __syncthreads();

  const int mrow = wv * 16;
  const short* w1m = w1t + (size_t)(64 + m) * 8192;
  const short* w2m = w2t + (size_t)(64 + m) * 8192;
  const float* b1m = b1 + (64 + m) * 128;
  const float* b2m = b2 + (64 + m) * 64;

  floatx4 acc2[4] = {};
  for (int hh = 0; hh < 2; ++hh) {
    floatx4 acc1[4] = {};
#pragma unroll
    for (int ks = 0; ks < 2; ++ks) {
      short8 a = *(const short8*)&zL[mrow + il][ks * 32 + q * 8];
#pragma unroll
      for (int nt = 0; nt < 4; ++nt) {
        short8 b = *(const short8*)(w1m + (hh * 64 + nt * 16 + il) * 64 + ks * 32 + q * 8);
        acc1[nt] = MFMA(a, b, acc1[nt]);
      }
    }
#pragma unroll
    for (int nt = 0; nt < 4; ++nt) {
      float bias = b1m[hh * 64 + nt * 16 + il];
#pragma unroll
      for (int rg = 0; rg < 4; ++rg) {
        hs[wv][q * 4 + rg][nt * 16 + il] = (short)bf16r(eluf(acc1[nt][rg] + bias));
      }
    }
    asm volatile("s_waitcnt lgkmcnt(0)" ::: "memory");
#pragma unroll
    for (int ks2 = 0; ks2 < 2; ++ks2) {
      short8 a2 = *(const short8*)&hs[wv][il][ks2 * 32 + q * 8];
#pragma unroll
      for (int nt2 = 0; nt2 < 4; ++nt2) {
        short8 b = *(const short8*)(w2m + (nt2 * 16 + il) * 128 + hh * 64 + ks2 * 32 + q * 8);
        acc2[nt2] = MFMA(a2, b, acc2[nt2]);
      }
    }
    asm volatile("s_waitcnt lgkmcnt(0)" ::: "memory");
  }
  // epilogue: bias + residual (bf16 z2 from zL), restage into hs, coalesced store
#pragma unroll
  for (int nt2 = 0; nt2 < 4; ++nt2) {
    const int j = nt2 * 16 + il;
    const float bias = b2m[j];
#pragma unroll
    for (int k = 0; k < 4; ++k) {
      float r = bf16f((unsigned short)zL[mrow + q * 4 + k][j]);
      hs[wv][q * 4 + k][j] = (short)bf16r(acc2[nt2][k] + bias + r);
    }
  }
  asm volatile("s_waitcnt lgkmcnt(0)" ::: "memory");
  const int rr = lane & 15;
  const int iq = lane >> 4;
#pragma unroll
  for (int t = 0; t < 4; ++t) {
    const uint2 v = *(const uint2*)&hs[wv][rr][t * 16 + iq * 4];
    *(uint2*)(y2 + ((size_t)(m * 8192 + R0 + mrow + rr)) * 64 + t * 16 + iq * 4) = v;
  }
}

// ---------------- K3: inverse shuffle + fp32 output ----------------
// out[r][i*64 + m] = y2[m][r][i].  WG = 4 rows, wave per row, LDS 64x64 transpose.
__global__ __launch_bounds__(256) void k3_unshuffle(
    const short* __restrict__ y2, float* __restrict__ out) {
  __shared__ __align__(16) short st[4][64][68];
  const int tid  = threadIdx.x;
  const int lane = tid & 63;
  const int wv   = tid >> 6;
  const int R    = blockIdx.x * 4 + wv;
  const int mq = lane >> 2;   // 0..15
  const int iq = lane & 3;    // 0..3
#pragma unroll
  for (int mt = 0; mt < 4; ++mt) {
#pragma unroll
    for (int it = 0; it < 4; ++it) {
      const int mm = mt * 16 + mq;
      const int i  = it * 16 + iq * 4;
      const uint2 v = *(const uint2*)(y2 + ((size_t)(mm * 8192 + R)) * 64 + i);
      *(uint2*)&st[wv][mm][i] = v;
    }
  }
  asm volatile("s_waitcnt vmcnt(0) lgkmcnt(0)" ::: "memory");
  float* orow = out + (size_t)R * 4096;
#pragma unroll 4
  for (int i = 0; i < 64; ++i) {
    orow[i * 64 + lane] = bf16f((unsigned short)st[wv][lane][i]);
  }
}

extern "C" void kernel_launch(void* const* d_in, const int* in_sizes, int n_in,
                              void* d_out, int out_size, void* d_ws, size_t ws_size,
                              hipStream_t stream) {
  const float* x  = (const float*)d_in[0];
  const float* w1 = (const float*)d_in[1];
  const float* b1 = (const float*)d_in[2];
  const float* w2 = (const float*)d_in[3];
  const float* b2 = (const float*)d_in[4];
  float* out = (float*)d_out;

  short* w1t = (short*)d_ws;
  short* w2t = w1t + (1u << 20);
  short* y1  = w2t + (1u << 20);
  short* y2  = y1 + (1ull << 25);

  hipLaunchKernelGGL(k0_prep,      dim3(4096), dim3(256), 0, stream, w1, w2, w1t, w2t);
  hipLaunchKernelGGL(k1_layer0,    dim3(4096), dim3(256), 0, stream, x, w1t, w2t, b1, b2, y1);
  hipLaunchKernelGGL(k2_layer1,    dim3(8192), dim3(256), 0, stream, y1, w1t, w2t, b1, b2, y2);
  hipLaunchKernelGGL(k3_unshuffle, dim3(2048), dim3(256), 0, stream, y2, out);
}